// Round 2
// baseline (883.882 us; speedup 1.0000x reference)
//
#include <hip/hip_runtime.h>
#include <hip/hip_bf16.h>

typedef __bf16 bf16_t;
typedef bf16_t bf16x8 __attribute__((ext_vector_type(8)));
typedef bf16_t bf16x4 __attribute__((ext_vector_type(4)));
typedef float f32x4 __attribute__((ext_vector_type(4)));

#define LDSK 40  // 32 + 8 pad (80B rows -> only 2-way bank aliasing, free)

// ---------------- weight transpose+convert: in fp32 (K x N) -> out bf16 (N x K)
__global__ __launch_bounds__(256) void wtrans_kernel(const float* __restrict__ in,
                                                     bf16_t* __restrict__ out, int K, int N)
{
    __shared__ float tile[32][33];
    const int n0 = blockIdx.x * 32, k0 = blockIdx.y * 32;
    const int tx = threadIdx.x & 31, ty = threadIdx.x >> 5;  // 32 x 8
#pragma unroll
    for (int i = 0; i < 32; i += 8)
        tile[ty + i][tx] = in[(long long)(k0 + ty + i) * N + n0 + tx];
    __syncthreads();
#pragma unroll
    for (int i = 0; i < 32; i += 8)
        out[(long long)(n0 + ty + i) * K + k0 + tx] = (bf16_t)tile[tx][ty + i];
}

// ---------------- 6 modulation linears on cond: out[(sig*8+b)*512 + n]
__global__ __launch_bounds__(256) void modsig_kernel(
    const float* __restrict__ cond,
    const float* __restrict__ w0, const float* __restrict__ w1, const float* __restrict__ w2,
    const float* __restrict__ w3, const float* __restrict__ w4, const float* __restrict__ w5,
    const float* __restrict__ c0, const float* __restrict__ c1, const float* __restrict__ c2,
    const float* __restrict__ c3, const float* __restrict__ c4, const float* __restrict__ c5,
    float* __restrict__ out)
{
    __shared__ float cs[512];
    const int sig = blockIdx.x >> 3, b = blockIdx.x & 7;
    const float* w; const float* bi;
    switch (sig) {
        case 0: w = w0; bi = c0; break;
        case 1: w = w1; bi = c1; break;
        case 2: w = w2; bi = c2; break;
        case 3: w = w3; bi = c3; break;
        case 4: w = w4; bi = c4; break;
        default: w = w5; bi = c5; break;
    }
    for (int i = threadIdx.x; i < 512; i += 256) cs[i] = cond[b * 512 + i];
    __syncthreads();
    for (int n = threadIdx.x; n < 512; n += 256) {
        float s = bi[n];
        for (int i = 0; i < 512; ++i) s = fmaf(cs[i], w[(long long)i * 512 + n], s);
        out[(long long)(sig * 8 + b) * 512 + n] = s;
    }
}

// ---------------- fused LayerNorm + AdaLN modulate, fp32 -> bf16
// out = (LN(x)*g + be) * (1 + gamma[b]) + beta[b]
__global__ __launch_bounds__(128) void ln_mod_kernel(
    const float* __restrict__ x, const float* __restrict__ g, const float* __restrict__ be,
    const float* __restrict__ gamma, const float* __restrict__ beta, bf16_t* __restrict__ out)
{
    const int row = blockIdx.x;       // 0..8191  (b*1024 + s)
    const int b = row >> 10;
    const int t = threadIdx.x;        // 128 threads, 4 floats each
    const float4 v = reinterpret_cast<const float4*>(x + (long long)row * 512)[t];
    float s = v.x + v.y + v.z + v.w;
    float ss = v.x * v.x + v.y * v.y + v.z * v.z + v.w * v.w;
    for (int o = 32; o; o >>= 1) { s += __shfl_xor(s, o); ss += __shfl_xor(ss, o); }
    __shared__ float red[4];
    if ((t & 63) == 0) { red[t >> 6] = s; red[2 + (t >> 6)] = ss; }
    __syncthreads();
    s = red[0] + red[1]; ss = red[2] + red[3];
    const float mu = s * (1.f / 512.f);
    const float rstd = rsqrtf(ss * (1.f / 512.f) - mu * mu + 1e-5f);
    const float4 gv = reinterpret_cast<const float4*>(g)[t];
    const float4 bv = reinterpret_cast<const float4*>(be)[t];
    const float4 ga = reinterpret_cast<const float4*>(gamma + b * 512)[t];
    const float4 bb = reinterpret_cast<const float4*>(beta + b * 512)[t];
    bf16x4 ov;
    ov[0] = (bf16_t)(((v.x - mu) * rstd * gv.x + bv.x) * (1.f + ga.x) + bb.x);
    ov[1] = (bf16_t)(((v.y - mu) * rstd * gv.y + bv.y) * (1.f + ga.y) + bb.y);
    ov[2] = (bf16_t)(((v.z - mu) * rstd * gv.z + bv.z) * (1.f + ga.z) + bb.z);
    ov[3] = (bf16_t)(((v.w - mu) * rstd * gv.w + bv.w) * (1.f + ga.w) + bb.w);
    reinterpret_cast<bf16x4*>(out + (long long)row * 512)[t] = ov;
}

// ---------------- row softmax on bf16 scores, scale applied at load (1/32)
__global__ __launch_bounds__(256) void softmax_kernel(bf16_t* __restrict__ S)
{
    const long long row = blockIdx.x;
    bf16_t* p = S + row * 1024;
    const int t = threadIdx.x;
    bf16x4 rv = reinterpret_cast<bf16x4*>(p)[t];
    float f[4];
#pragma unroll
    for (int i = 0; i < 4; ++i) f[i] = (float)rv[i] * 0.03125f;
    float m = fmaxf(fmaxf(f[0], f[1]), fmaxf(f[2], f[3]));
    for (int o = 32; o; o >>= 1) m = fmaxf(m, __shfl_xor(m, o));
    __shared__ float redm[4];
    __shared__ float reds[4];
    if ((t & 63) == 0) redm[t >> 6] = m;
    __syncthreads();
    m = fmaxf(fmaxf(redm[0], redm[1]), fmaxf(redm[2], redm[3]));
    float e[4]; float s = 0.f;
#pragma unroll
    for (int i = 0; i < 4; ++i) { e[i] = __expf(f[i] - m); s += e[i]; }
    for (int o = 32; o; o >>= 1) s += __shfl_xor(s, o);
    if ((t & 63) == 0) reds[t >> 6] = s;
    __syncthreads();
    s = reds[0] + reds[1] + reds[2] + reds[3];
    const float r = 1.f / s;
    bf16x4 ov;
#pragma unroll
    for (int i = 0; i < 4; ++i) ov[i] = (bf16_t)(e[i] * r);
    reinterpret_cast<bf16x4*>(p)[t] = ov;
}

// ---------------- 128x128x32 bf16 MFMA GEMM, C = A * B^T (B stored N x K)
// batch base = (bz>>3)*sXb + (bz&7)*sXh
// EPI 0: bf16 store (+bias)     EPI 1: relu -> bf16 (+bias)
// EPI 2: f32 store: resid + (acc+bias)*alpha[b*512+gn]   (ldc=512, M=8192)
// EPI 3: bf16 store transposed-V layout: [((gm>>10)*8+(gn>>9))*512+(gn&511)]*1024+(gm&1023)
template <int EPI>
__global__ __launch_bounds__(256) void gemm128_kernel(
    const bf16_t* __restrict__ A, const bf16_t* __restrict__ B,
    const float* __restrict__ bias, void* Cout,
    const float* resid, const float* __restrict__ alpha,
    int M, int N, int K, int lda, int ldb, int ldc,
    long long sAb, long long sAh, long long sBb, long long sBh,
    long long sCb, long long sCh)
{
    const int bz = blockIdx.z;
    const long long aBase = (long long)(bz >> 3) * sAb + (long long)(bz & 7) * sAh;
    const long long bBase = (long long)(bz >> 3) * sBb + (long long)(bz & 7) * sBh;
    const long long cBase = (long long)(bz >> 3) * sCb + (long long)(bz & 7) * sCh;
    const int m0 = blockIdx.y * 128, n0 = blockIdx.x * 128;
    const int tid = threadIdx.x, lane = tid & 63, wid = tid >> 6;
    const int wr = wid >> 1, wc = wid & 1;

    __shared__ bf16_t As[128][LDSK];
    __shared__ bf16_t Bs[128][LDSK];

    f32x4 acc[4][4];
#pragma unroll
    for (int m = 0; m < 4; ++m)
#pragma unroll
        for (int n = 0; n < 4; ++n) acc[m][n] = (f32x4){0.f, 0.f, 0.f, 0.f};

    const int srow = tid >> 2;            // 0..63
    const int skoff = (tid & 3) * 8;      // 0,8,16,24
    const long long aRow0 = aBase + (long long)(m0 + srow) * lda + skoff;
    const long long aRow1 = aBase + (long long)(m0 + srow + 64) * lda + skoff;
    const long long bRow0 = bBase + (long long)(n0 + srow) * ldb + skoff;
    const long long bRow1 = bBase + (long long)(n0 + srow + 64) * ldb + skoff;
    const int frow = lane & 15;
    const int fko = (lane >> 4) << 3;

    for (int kt = 0; kt < K; kt += 32) {
        const uint4 a0 = *reinterpret_cast<const uint4*>(A + aRow0 + kt);
        const uint4 a1 = *reinterpret_cast<const uint4*>(A + aRow1 + kt);
        const uint4 b0 = *reinterpret_cast<const uint4*>(B + bRow0 + kt);
        const uint4 b1 = *reinterpret_cast<const uint4*>(B + bRow1 + kt);
        *reinterpret_cast<uint4*>(&As[srow][skoff]) = a0;
        *reinterpret_cast<uint4*>(&As[srow + 64][skoff]) = a1;
        *reinterpret_cast<uint4*>(&Bs[srow][skoff]) = b0;
        *reinterpret_cast<uint4*>(&Bs[srow + 64][skoff]) = b1;
        __syncthreads();
        bf16x8 af[4], bfv[4];
#pragma unroll
        for (int m = 0; m < 4; ++m)
            af[m] = *reinterpret_cast<const bf16x8*>(&As[wr * 64 + m * 16 + frow][fko]);
#pragma unroll
        for (int n = 0; n < 4; ++n)
            bfv[n] = *reinterpret_cast<const bf16x8*>(&Bs[wc * 64 + n * 16 + frow][fko]);
#pragma unroll
        for (int m = 0; m < 4; ++m)
#pragma unroll
            for (int n = 0; n < 4; ++n)
                acc[m][n] = __builtin_amdgcn_mfma_f32_16x16x32_bf16(af[m], bfv[n], acc[m][n], 0, 0, 0);
        __syncthreads();
    }

#pragma unroll
    for (int m = 0; m < 4; ++m) {
        const int gm = m0 + wr * 64 + m * 16 + ((lane >> 4) << 2);
#pragma unroll
        for (int n = 0; n < 4; ++n) {
            const int gn = n0 + wc * 64 + n * 16 + (lane & 15);
            const float bb = bias ? bias[gn] : 0.f;
#pragma unroll
            for (int j = 0; j < 4; ++j) {
                const float v = acc[m][n][j] + bb;
                const int gmj = gm + j;
                if (EPI == 0) {
                    ((bf16_t*)Cout)[cBase + (long long)gmj * ldc + gn] = (bf16_t)v;
                } else if (EPI == 1) {
                    ((bf16_t*)Cout)[cBase + (long long)gmj * ldc + gn] = (bf16_t)fmaxf(v, 0.f);
                } else if (EPI == 2) {
                    const long long ci = (long long)gmj * ldc + gn;
                    ((float*)Cout)[ci] = resid[ci] + v * alpha[(gmj >> 10) * 512 + gn];
                } else {
                    const long long ci =
                        (long long)(((gmj >> 10) * 8 + (gn >> 9)) * 512 + (gn & 511)) * 1024 + (gmj & 1023);
                    ((bf16_t*)Cout)[ci] = (bf16_t)v;
                }
            }
        }
    }
}

extern "C" void kernel_launch(void* const* d_in, const int* in_sizes, int n_in,
                              void* d_out, int out_size, void* d_ws, size_t ws_size,
                              hipStream_t stream)
{
    const float* x    = (const float*)d_in[0];
    const float* cond = (const float*)d_in[1];
    const float* g1w  = (const float*)d_in[2];  const float* g1b  = (const float*)d_in[3];
    const float* be1w = (const float*)d_in[4];  const float* be1b = (const float*)d_in[5];
    const float* a1w  = (const float*)d_in[6];  const float* a1b  = (const float*)d_in[7];
    const float* g2w  = (const float*)d_in[8];  const float* g2b  = (const float*)d_in[9];
    const float* be2w = (const float*)d_in[10]; const float* be2b = (const float*)d_in[11];
    const float* a2w  = (const float*)d_in[12]; const float* a2b  = (const float*)d_in[13];
    const float* ln1g = (const float*)d_in[14]; const float* ln1b = (const float*)d_in[15];
    const float* ln2g = (const float*)d_in[16]; const float* ln2b = (const float*)d_in[17];
    const float* wq   = (const float*)d_in[18]; const float* bq   = (const float*)d_in[19];
    const float* wk   = (const float*)d_in[20]; const float* bk   = (const float*)d_in[21];
    const float* wv   = (const float*)d_in[22]; const float* bv   = (const float*)d_in[23];
    const float* lvw  = (const float*)d_in[24]; const float* lvb  = (const float*)d_in[25];
    const float* f1w  = (const float*)d_in[26]; const float* f1b  = (const float*)d_in[27];
    const float* f2w  = (const float*)d_in[28]; const float* f2b  = (const float*)d_in[29];
    (void)in_sizes; (void)n_in; (void)out_size;

    // workspace layout (bytes)
    char* w8 = (char*)d_ws;
    float*  mod  = (float*)(w8);                                   //  98304
    bf16_t* wqT  = (bf16_t*)(w8 + 98304);                          // 4096x512 bf16
    bf16_t* wkT  = (bf16_t*)(w8 + 98304 + 4194304);
    bf16_t* wvT  = (bf16_t*)(w8 + 98304 + 2 * 4194304);
    bf16_t* lvwT = (bf16_t*)(w8 + 98304 + 3 * 4194304);            // 512x4096
    bf16_t* f1wT = (bf16_t*)(w8 + 98304 + 4 * 4194304);            // 2048x512
    bf16_t* f2wT = (bf16_t*)(w8 + 98304 + 4 * 4194304 + 2097152);  // 512x2048
    bf16_t* ybf  = (bf16_t*)(w8 + 98304 + 4 * 4194304 + 2 * 2097152);           // 8192x512
    bf16_t* qb   = (bf16_t*)(w8 + 98304 + 4 * 4194304 + 2 * 2097152 + 8388608); // (b,s,h,e)
    bf16_t* kb   = qb + 33554432;    // (b,s,h,e); later reused for O
    bf16_t* vtb  = kb + 33554432;    // V stored transposed: (b,h,e,s)
    bf16_t* Sb   = vtb + 33554432;   // score chunk: nb * 8 * 1024 * 1024 bf16
    const size_t baseBytes = 230785024ULL;
    const size_t chunkBytes = 16777216ULL;  // one batch of scores (8*1024*1024*2)
    int nb = 1;
    if (ws_size > baseBytes) {
        size_t a = (ws_size - baseBytes) / chunkBytes;
        nb = (a >= 8) ? 8 : (a < 1 ? 1 : (int)a);
    }

    const dim3 blk(256);
    // weights -> bf16 transposed
    wtrans_kernel<<<dim3(128, 16), blk, 0, stream>>>(wq, wqT, 512, 4096);
    wtrans_kernel<<<dim3(128, 16), blk, 0, stream>>>(wk, wkT, 512, 4096);
    wtrans_kernel<<<dim3(128, 16), blk, 0, stream>>>(wv, wvT, 512, 4096);
    wtrans_kernel<<<dim3(16, 128), blk, 0, stream>>>(lvw, lvwT, 4096, 512);
    wtrans_kernel<<<dim3(64, 16), blk, 0, stream>>>(f1w, f1wT, 512, 2048);
    wtrans_kernel<<<dim3(16, 64), blk, 0, stream>>>(f2w, f2wT, 2048, 512);
    // modulation signals
    modsig_kernel<<<48, blk, 0, stream>>>(cond, g1w, be1w, a1w, g2w, be2w, a2w,
                                          g1b, be1b, a1b, g2b, be2b, a2b, mod);
    // LN1 + modulate -> y (bf16)
    ln_mod_kernel<<<8192, 128, 0, stream>>>(x, ln1g, ln1b, mod, mod + 4096, ybf);
    // QKV projections (V stored transposed)
    gemm128_kernel<0><<<dim3(32, 64, 1), blk, 0, stream>>>(ybf, wqT, bq, qb, nullptr, nullptr,
        8192, 4096, 512, 512, 512, 4096, 0, 0, 0, 0, 0, 0);
    gemm128_kernel<0><<<dim3(32, 64, 1), blk, 0, stream>>>(ybf, wkT, bk, kb, nullptr, nullptr,
        8192, 4096, 512, 512, 512, 4096, 0, 0, 0, 0, 0, 0);
    gemm128_kernel<3><<<dim3(32, 64, 1), blk, 0, stream>>>(ybf, wvT, bv, vtb, nullptr, nullptr,
        8192, 4096, 512, 512, 512, 0, 0, 0, 0, 0, 0, 0);
    // attention, chunked over batch b
    for (int c0 = 0; c0 < 8; c0 += nb) {
        const int cb = (8 - c0 < nb) ? (8 - c0) : nb;
        // S = Q K^T  (per (b,h))
        gemm128_kernel<0><<<dim3(8, 8, cb * 8), blk, 0, stream>>>(
            qb + (long long)c0 * 4194304, kb + (long long)c0 * 4194304, nullptr, Sb, nullptr, nullptr,
            1024, 1024, 512, 4096, 4096, 1024,
            4194304LL, 512LL, 4194304LL, 512LL, 8388608LL, 1048576LL);
        softmax_kernel<<<cb * 8192, blk, 0, stream>>>(Sb);
        // O = P V   (O overwrites this batch's K region, layout (b,s,h,e))
        gemm128_kernel<0><<<dim3(4, 8, cb * 8), blk, 0, stream>>>(
            Sb, vtb + (long long)c0 * 4194304, nullptr, kb + (long long)c0 * 4194304, nullptr, nullptr,
            1024, 512, 1024, 1024, 1024, 4096,
            8388608LL, 1048576LL, 4194304LL, 524288LL, 4194304LL, 512LL);
    }
    // y2 = x + (O @ lvw + lvb) * alpha1  -> d_out (fp32)
    gemm128_kernel<2><<<dim3(4, 64, 1), blk, 0, stream>>>(kb, lvwT, lvb, d_out, x, mod + 8192,
        8192, 512, 4096, 4096, 4096, 512, 0, 0, 0, 0, 0, 0);
    // LN2 + modulate -> z (bf16)
    ln_mod_kernel<<<8192, 128, 0, stream>>>((const float*)d_out, ln2g, ln2b,
                                            mod + 12288, mod + 16384, ybf);
    // FFN
    gemm128_kernel<1><<<dim3(16, 64, 1), blk, 0, stream>>>(ybf, f1wT, f1b, qb, nullptr, nullptr,
        8192, 2048, 512, 512, 512, 2048, 0, 0, 0, 0, 0, 0);
    gemm128_kernel<2><<<dim3(4, 64, 1), blk, 0, stream>>>(qb, f2wT, f2b, d_out,
        (const float*)d_out, mod + 20480,
        8192, 512, 2048, 2048, 2048, 512, 0, 0, 0, 0, 0, 0);
}

// Round 3
// 729.051 us; speedup vs baseline: 1.2124x; 1.2124x over previous
//
#include <hip/hip_runtime.h>
#include <hip/hip_bf16.h>

typedef __bf16 bf16_t;
typedef bf16_t bf16x8 __attribute__((ext_vector_type(8)));
typedef bf16_t bf16x4 __attribute__((ext_vector_type(4)));
typedef float f32x4 __attribute__((ext_vector_type(4)));

#define LDSK 40  // 32 + 8 pad (80B rows -> only 2-way bank aliasing, free)

typedef const __attribute__((address_space(1))) void GV;
typedef __attribute__((address_space(3))) void LV;

__device__ __forceinline__ void gload_lds16(const bf16_t* gsrc, bf16_t* ldst) {
    __builtin_amdgcn_global_load_lds((GV*)gsrc, (LV*)ldst, 16, 0, 0);
}

// ---------------- weight transpose+convert: in fp32 (K x N) -> out bf16 (N x K)
__global__ __launch_bounds__(256) void wtrans_kernel(const float* __restrict__ in,
                                                     bf16_t* __restrict__ out, int K, int N)
{
    __shared__ float tile[32][33];
    const int n0 = blockIdx.x * 32, k0 = blockIdx.y * 32;
    const int tx = threadIdx.x & 31, ty = threadIdx.x >> 5;  // 32 x 8
#pragma unroll
    for (int i = 0; i < 32; i += 8)
        tile[ty + i][tx] = in[(long long)(k0 + ty + i) * N + n0 + tx];
    __syncthreads();
#pragma unroll
    for (int i = 0; i < 32; i += 8)
        out[(long long)(n0 + ty + i) * K + k0 + tx] = (bf16_t)tile[tx][ty + i];
}

// ---------------- 6 modulation linears on cond: out[(sig*8+b)*512 + n]
__global__ __launch_bounds__(256) void modsig_kernel(
    const float* __restrict__ cond,
    const float* __restrict__ w0, const float* __restrict__ w1, const float* __restrict__ w2,
    const float* __restrict__ w3, const float* __restrict__ w4, const float* __restrict__ w5,
    const float* __restrict__ c0, const float* __restrict__ c1, const float* __restrict__ c2,
    const float* __restrict__ c3, const float* __restrict__ c4, const float* __restrict__ c5,
    float* __restrict__ out)
{
    __shared__ float cs[512];
    const int sig = blockIdx.x >> 3, b = blockIdx.x & 7;
    const float* w; const float* bi;
    switch (sig) {
        case 0: w = w0; bi = c0; break;
        case 1: w = w1; bi = c1; break;
        case 2: w = w2; bi = c2; break;
        case 3: w = w3; bi = c3; break;
        case 4: w = w4; bi = c4; break;
        default: w = w5; bi = c5; break;
    }
    for (int i = threadIdx.x; i < 512; i += 256) cs[i] = cond[b * 512 + i];
    __syncthreads();
    for (int n = threadIdx.x; n < 512; n += 256) {
        float s = bi[n];
        for (int i = 0; i < 512; ++i) s = fmaf(cs[i], w[(long long)i * 512 + n], s);
        out[(long long)(sig * 8 + b) * 512 + n] = s;
    }
}

// ---------------- fused LayerNorm + AdaLN modulate, fp32 -> bf16
__global__ __launch_bounds__(128) void ln_mod_kernel(
    const float* __restrict__ x, const float* __restrict__ g, const float* __restrict__ be,
    const float* __restrict__ gamma, const float* __restrict__ beta, bf16_t* __restrict__ out)
{
    const int row = blockIdx.x;
    const int b = row >> 10;
    const int t = threadIdx.x;
    const float4 v = reinterpret_cast<const float4*>(x + (long long)row * 512)[t];
    float s = v.x + v.y + v.z + v.w;
    float ss = v.x * v.x + v.y * v.y + v.z * v.z + v.w * v.w;
    for (int o = 32; o; o >>= 1) { s += __shfl_xor(s, o); ss += __shfl_xor(ss, o); }
    __shared__ float red[4];
    if ((t & 63) == 0) { red[t >> 6] = s; red[2 + (t >> 6)] = ss; }
    __syncthreads();
    s = red[0] + red[1]; ss = red[2] + red[3];
    const float mu = s * (1.f / 512.f);
    const float rstd = rsqrtf(ss * (1.f / 512.f) - mu * mu + 1e-5f);
    const float4 gv = reinterpret_cast<const float4*>(g)[t];
    const float4 bv = reinterpret_cast<const float4*>(be)[t];
    const float4 ga = reinterpret_cast<const float4*>(gamma + b * 512)[t];
    const float4 bb = reinterpret_cast<const float4*>(beta + b * 512)[t];
    bf16x4 ov;
    ov[0] = (bf16_t)(((v.x - mu) * rstd * gv.x + bv.x) * (1.f + ga.x) + bb.x);
    ov[1] = (bf16_t)(((v.y - mu) * rstd * gv.y + bv.y) * (1.f + ga.y) + bb.y);
    ov[2] = (bf16_t)(((v.z - mu) * rstd * gv.z + bv.z) * (1.f + ga.z) + bb.z);
    ov[3] = (bf16_t)(((v.w - mu) * rstd * gv.w + bv.w) * (1.f + ga.w) + bb.w);
    reinterpret_cast<bf16x4*>(out + (long long)row * 512)[t] = ov;
}

// ---------------- 128x128x32 bf16 MFMA GEMM, C = A * B^T (B stored N x K)
// EPI 0: bf16 store (+bias)  EPI 1: relu->bf16 (+bias)
// EPI 3: bf16 store transposed-V layout
template <int EPI>
__global__ __launch_bounds__(256) void gemm128_kernel(
    const bf16_t* __restrict__ A, const bf16_t* __restrict__ B,
    const float* __restrict__ bias, void* Cout,
    int M, int N, int K, int lda, int ldb, int ldc)
{
    const int m0 = blockIdx.y * 128, n0 = blockIdx.x * 128;
    const int tid = threadIdx.x, lane = tid & 63, wid = tid >> 6;
    const int wr = wid >> 1, wc = wid & 1;

    __shared__ bf16_t As[128][LDSK];
    __shared__ bf16_t Bs[128][LDSK];

    f32x4 acc[4][4];
#pragma unroll
    for (int m = 0; m < 4; ++m)
#pragma unroll
        for (int n = 0; n < 4; ++n) acc[m][n] = (f32x4){0.f, 0.f, 0.f, 0.f};

    const int srow = tid >> 2;
    const int skoff = (tid & 3) * 8;
    const long long aRow0 = (long long)(m0 + srow) * lda + skoff;
    const long long aRow1 = (long long)(m0 + srow + 64) * lda + skoff;
    const long long bRow0 = (long long)(n0 + srow) * ldb + skoff;
    const long long bRow1 = (long long)(n0 + srow + 64) * ldb + skoff;
    const int frow = lane & 15;
    const int fko = (lane >> 4) << 3;

    for (int kt = 0; kt < K; kt += 32) {
        const uint4 a0 = *reinterpret_cast<const uint4*>(A + aRow0 + kt);
        const uint4 a1 = *reinterpret_cast<const uint4*>(A + aRow1 + kt);
        const uint4 b0 = *reinterpret_cast<const uint4*>(B + bRow0 + kt);
        const uint4 b1 = *reinterpret_cast<const uint4*>(B + bRow1 + kt);
        *reinterpret_cast<uint4*>(&As[srow][skoff]) = a0;
        *reinterpret_cast<uint4*>(&As[srow + 64][skoff]) = a1;
        *reinterpret_cast<uint4*>(&Bs[srow][skoff]) = b0;
        *reinterpret_cast<uint4*>(&Bs[srow + 64][skoff]) = b1;
        __syncthreads();
        bf16x8 af[4], bfv[4];
#pragma unroll
        for (int m = 0; m < 4; ++m)
            af[m] = *reinterpret_cast<const bf16x8*>(&As[wr * 64 + m * 16 + frow][fko]);
#pragma unroll
        for (int n = 0; n < 4; ++n)
            bfv[n] = *reinterpret_cast<const bf16x8*>(&Bs[wc * 64 + n * 16 + frow][fko]);
#pragma unroll
        for (int m = 0; m < 4; ++m)
#pragma unroll
            for (int n = 0; n < 4; ++n)
                acc[m][n] = __builtin_amdgcn_mfma_f32_16x16x32_bf16(af[m], bfv[n], acc[m][n], 0, 0, 0);
        __syncthreads();
    }

#pragma unroll
    for (int m = 0; m < 4; ++m) {
        const int gm = m0 + wr * 64 + m * 16 + ((lane >> 4) << 2);
#pragma unroll
        for (int n = 0; n < 4; ++n) {
            const int gn = n0 + wc * 64 + n * 16 + (lane & 15);
            const float bb = bias ? bias[gn] : 0.f;
#pragma unroll
            for (int j = 0; j < 4; ++j) {
                const float v = acc[m][n][j] + bb;
                const int gmj = gm + j;
                if (EPI == 0) {
                    ((bf16_t*)Cout)[(long long)gmj * ldc + gn] = (bf16_t)v;
                } else if (EPI == 1) {
                    ((bf16_t*)Cout)[(long long)gmj * ldc + gn] = (bf16_t)fmaxf(v, 0.f);
                } else {
                    const long long ci =
                        (long long)(((gmj >> 10) * 8 + (gn >> 9)) * 512 + (gn & 511)) * 1024 + (gmj & 1023);
                    ((bf16_t*)Cout)[ci] = (bf16_t)v;
                }
            }
        }
    }
}

// ---------------- 64x128x32 GEMM, EPI2: out = resid + (acc+bias)*alpha  (f32, ldc=512)
__global__ __launch_bounds__(256) void gemm64_kernel(
    const bf16_t* __restrict__ A, const bf16_t* __restrict__ B,
    const float* __restrict__ bias, float* __restrict__ Cout,
    const float* __restrict__ resid, const float* __restrict__ alpha,
    int M, int N, int K, int lda, int ldb)
{
    const int m0 = blockIdx.y * 64, n0 = blockIdx.x * 128;
    const int tid = threadIdx.x, lane = tid & 63, wid = tid >> 6;
    const int wr = wid >> 1, wc = wid & 1;

    __shared__ bf16_t As[64][LDSK];
    __shared__ bf16_t Bs[128][LDSK];

    f32x4 acc[2][4];
#pragma unroll
    for (int m = 0; m < 2; ++m)
#pragma unroll
        for (int n = 0; n < 4; ++n) acc[m][n] = (f32x4){0.f, 0.f, 0.f, 0.f};

    const int srow = tid >> 2;
    const int skoff = (tid & 3) * 8;
    const long long aRow = (long long)(m0 + srow) * lda + skoff;
    const long long bRow0 = (long long)(n0 + srow) * ldb + skoff;
    const long long bRow1 = (long long)(n0 + srow + 64) * ldb + skoff;
    const int frow = lane & 15;
    const int fko = (lane >> 4) << 3;

    for (int kt = 0; kt < K; kt += 32) {
        const uint4 a0 = *reinterpret_cast<const uint4*>(A + aRow + kt);
        const uint4 b0 = *reinterpret_cast<const uint4*>(B + bRow0 + kt);
        const uint4 b1 = *reinterpret_cast<const uint4*>(B + bRow1 + kt);
        *reinterpret_cast<uint4*>(&As[srow][skoff]) = a0;
        *reinterpret_cast<uint4*>(&Bs[srow][skoff]) = b0;
        *reinterpret_cast<uint4*>(&Bs[srow + 64][skoff]) = b1;
        __syncthreads();
        bf16x8 af[2], bfv[4];
#pragma unroll
        for (int m = 0; m < 2; ++m)
            af[m] = *reinterpret_cast<const bf16x8*>(&As[wr * 32 + m * 16 + frow][fko]);
#pragma unroll
        for (int n = 0; n < 4; ++n)
            bfv[n] = *reinterpret_cast<const bf16x8*>(&Bs[wc * 64 + n * 16 + frow][fko]);
#pragma unroll
        for (int m = 0; m < 2; ++m)
#pragma unroll
            for (int n = 0; n < 4; ++n)
                acc[m][n] = __builtin_amdgcn_mfma_f32_16x16x32_bf16(af[m], bfv[n], acc[m][n], 0, 0, 0);
        __syncthreads();
    }

#pragma unroll
    for (int m = 0; m < 2; ++m) {
        const int gm = m0 + wr * 32 + m * 16 + ((lane >> 4) << 2);
#pragma unroll
        for (int n = 0; n < 4; ++n) {
            const int gn = n0 + wc * 64 + n * 16 + (lane & 15);
            const float bb = bias[gn];
#pragma unroll
            for (int j = 0; j < 4; ++j) {
                const int gmj = gm + j;
                const long long ci = (long long)gmj * 512 + gn;
                Cout[ci] = resid[ci] + (acc[m][n][j] + bb) * alpha[(gmj >> 10) * 512 + gn];
            }
        }
    }
}

// ---------------- fused flash attention
// grid 1024: xcd=bid&7, idx=bid>>3, qt=idx&15, bhl=idx>>4, bh=xcd*8+bhl
// per block: (b,h), 64 q-rows; KV loop 16 iters of 64 keys.
// S computed transposed via mfma(K,Q); O accumulated transposed (e rows, q cols);
// O written over qb (same rows this block read).
#define FA_LDS 140288
__global__ __launch_bounds__(512, 2) void flash_kernel(
    bf16_t* __restrict__ qb, const bf16_t* __restrict__ kb, const bf16_t* __restrict__ vtb)
{
    extern __shared__ char smem[];
    bf16_t* Qs = (bf16_t*)smem;               // [64][512] chunk-swizzled (16B chunk ^ (row&7))
    bf16_t* KVs = (bf16_t*)(smem + 65536);    // K: [64][512] same swizzle; V: [512][64] (16B chunk ^ (e&7))
    char* PB = smem + 131072;                 // P: [64 q][64 k] bf16, 8B granule ^ ((q&7)<<1)
    float* pmax = (float*)(smem + 139264);    // [2][64]
    float* psum = (float*)(smem + 139776);    // [2][64]

    const int bid = blockIdx.x;
    const int xcd = bid & 7, idx = bid >> 3;
    const int qt = idx & 15, bhl = idx >> 4;
    const int bh = xcd * 8 + bhl;
    const int b = bh >> 3, h = bh & 7;
    const int q0 = qt * 64;
    const int tid = threadIdx.x, lane = tid & 63, wid = tid >> 6;
    const int laneq = lane & 15, lx = lane & 7, lg = lane >> 4;
    // S-role (Sᵀ 64k x 64q): wk = k-half, wq = q-quarter
    const int wk = wid >> 2, wq = wid & 3;
    // PV-role (Oᵀ 512e x 64q): we = e-quarter, wq2 = q-half
    const int we = wid & 3, wq2 = wid >> 2;

    // ---- stage Q once (source chunk pre-swizzled so LDS linear dest = swizzled layout)
#pragma unroll
    for (int r = 0; r < 8; ++r) {
        const int row = r * 8 + wid;
        const bf16_t* src = qb + ((long long)(b * 1024 + q0 + row) * 8 + h) * 512
                            + ((lane ^ (row & 7)) << 3);
        gload_lds16(src, Qs + row * 512);
    }

    f32x4 accA[8], accB[8];
#pragma unroll
    for (int e = 0; e < 8; ++e) { accA[e] = (f32x4){0.f,0.f,0.f,0.f}; accB[e] = (f32x4){0.f,0.f,0.f,0.f}; }
    float mS = -1e30f, mPA = -1e30f, mPB = -1e30f, lA = 0.f, lB = 0.f;

    const int rA0 = wk * 32 + laneq, rA1 = rA0 + 16;      // Sᵀ k-rows
    const int rQ = wq * 16 + laneq;                        // q row in Qs
    const int qi = wq * 16 + laneq;                        // this lane's q (S role)
    const int qA = wq2 * 32 + laneq, qB = qA + 16;         // this lane's q's (PV role)

    for (int t = 0; t < 16; ++t) {
        const int kv0 = t * 64;
        // ---- stage K tile
#pragma unroll
        for (int r = 0; r < 8; ++r) {
            const int row = r * 8 + wid;
            const bf16_t* src = kb + ((long long)(b * 1024 + kv0 + row) * 8 + h) * 512
                                + ((lane ^ (row & 7)) << 3);
            gload_lds16(src, KVs + row * 512);
        }
        __syncthreads();  // bar A: K (and Q at t=0) ready

        // ---- Sᵀ = K·Qᵀ
        f32x4 s0 = (f32x4){0.f,0.f,0.f,0.f}, s1 = (f32x4){0.f,0.f,0.f,0.f};
        const char* KsB = (const char*)KVs;
        const char* QsB = (const char*)Qs;
#pragma unroll 4
        for (int ks = 0; ks < 16; ++ks) {
            const int cb = ks * 4 + lg;
            const int co = (cb ^ lx) << 4;
            bf16x8 a0 = *(const bf16x8*)(KsB + rA0 * 1024 + co);
            bf16x8 a1 = *(const bf16x8*)(KsB + rA1 * 1024 + co);
            bf16x8 bq = *(const bf16x8*)(QsB + rQ * 1024 + co);
            s0 = __builtin_amdgcn_mfma_f32_16x16x32_bf16(a0, bq, s0, 0, 0, 0);
            s1 = __builtin_amdgcn_mfma_f32_16x16x32_bf16(a1, bq, s1, 0, 0, 0);
        }
        // ---- softmax partial max
        float sc[8];
#pragma unroll
        for (int j = 0; j < 4; ++j) { sc[j] = s0[j] * 0.03125f; sc[4 + j] = s1[j] * 0.03125f; }
        float mloc = sc[0];
#pragma unroll
        for (int j = 1; j < 8; ++j) mloc = fmaxf(mloc, sc[j]);
        mloc = fmaxf(mloc, __shfl_xor(mloc, 16));
        mloc = fmaxf(mloc, __shfl_xor(mloc, 32));
        if (lane < 16) pmax[wk * 64 + wq * 16 + lane] = mloc;
        __syncthreads();  // bar B: pmax ready; all K reads done

        // ---- P = exp(S - m_new), partial sums; stage V into KVs
        const float mnew = fmaxf(mS, fmaxf(pmax[qi], pmax[64 + qi]));
        mS = mnew;
        float pe[8]; float sl = 0.f;
#pragma unroll
        for (int j = 0; j < 8; ++j) { pe[j] = __expf(sc[j] - mnew); sl += pe[j]; }
        sl += __shfl_xor(sl, 16);
        sl += __shfl_xor(sl, 32);
        if (lane < 16) psum[wk * 64 + wq * 16 + lane] = sl;
        {
            bf16x4 p0, p1;
#pragma unroll
            for (int j = 0; j < 4; ++j) { p0[j] = (bf16_t)pe[j]; p1[j] = (bf16_t)pe[4 + j]; }
            const int kc0 = wk * 8 + lg, kc1 = kc0 + 4;
            const int qx = (qi & 7) << 1;
            *(bf16x4*)(PB + qi * 128 + ((kc0 ^ qx) << 3)) = p0;
            *(bf16x4*)(PB + qi * 128 + ((kc1 ^ qx) << 3)) = p1;
        }
#pragma unroll
        for (int r = 0; r < 8; ++r) {
            const int e = r * 64 + wid * 8 + (lane >> 3);
            const bf16_t* src = vtb + ((long long)bh * 512 + e) * 1024 + kv0
                                + (((lane & 7) ^ (e & 7)) << 3);
            gload_lds16(src, KVs + (r * 64 + wid * 8) * 64);
        }
        __syncthreads();  // bar C: psum, P, V ready

        // ---- online-stat update + rescale + PV
        {
            const float mnA = fmaxf(mPA, fmaxf(pmax[qA], pmax[64 + qA]));
            const float rA = __expf(mPA - mnA);
            mPA = mnA;
            lA = lA * rA + psum[qA] + psum[64 + qA];
            const float mnB = fmaxf(mPB, fmaxf(pmax[qB], pmax[64 + qB]));
            const float rB = __expf(mPB - mnB);
            mPB = mnB;
            lB = lB * rB + psum[qB] + psum[64 + qB];
#pragma unroll
            for (int e = 0; e < 8; ++e) {
#pragma unroll
                for (int j = 0; j < 4; ++j) { accA[e][j] *= rA; accB[e][j] *= rB; }
            }
        }
        const char* VB = (const char*)KVs;
        const int qxA = (qA & 7) << 1, qxB = (qB & 7) << 1;
#pragma unroll
        for (int ks2 = 0; ks2 < 2; ++ks2) {
            const int kcp = ks2 * 8 + lg * 2;
            bf16x8 pA = *(const bf16x8*)(PB + qA * 128 + ((kcp ^ qxA) << 3));
            bf16x8 pBv = *(const bf16x8*)(PB + qB * 128 + ((kcp ^ qxB) << 3));
            const int kcv = ks2 * 4 + lg;
#pragma unroll
            for (int ef = 0; ef < 8; ++ef) {
                const int re = we * 128 + ef * 16 + laneq;
                bf16x8 av = *(const bf16x8*)(VB + re * 128 + ((kcv ^ lx) << 4));
                accA[ef] = __builtin_amdgcn_mfma_f32_16x16x32_bf16(av, pA, accA[ef], 0, 0, 0);
                accB[ef] = __builtin_amdgcn_mfma_f32_16x16x32_bf16(av, pBv, accB[ef], 0, 0, 0);
            }
        }
        __syncthreads();  // bar D: P/V reads done before next overwrite
    }

    // ---- epilogue: O = acc / l, store over qb
    const float iA = 1.f / lA, iB = 1.f / lB;
#pragma unroll
    for (int ef = 0; ef < 8; ++ef) {
        const int e0 = we * 128 + ef * 16 + lg * 4;
        bf16x4 oA, oB;
#pragma unroll
        for (int j = 0; j < 4; ++j) { oA[j] = (bf16_t)(accA[ef][j] * iA); oB[j] = (bf16_t)(accB[ef][j] * iB); }
        *(bf16x4*)(qb + ((long long)(b * 1024 + q0 + qA) * 8 + h) * 512 + e0) = oA;
        *(bf16x4*)(qb + ((long long)(b * 1024 + q0 + qB) * 8 + h) * 512 + e0) = oB;
    }
}

extern "C" void kernel_launch(void* const* d_in, const int* in_sizes, int n_in,
                              void* d_out, int out_size, void* d_ws, size_t ws_size,
                              hipStream_t stream)
{
    const float* x    = (const float*)d_in[0];
    const float* cond = (const float*)d_in[1];
    const float* g1w  = (const float*)d_in[2];  const float* g1b  = (const float*)d_in[3];
    const float* be1w = (const float*)d_in[4];  const float* be1b = (const float*)d_in[5];
    const float* a1w  = (const float*)d_in[6];  const float* a1b  = (const float*)d_in[7];
    const float* g2w  = (const float*)d_in[8];  const float* g2b  = (const float*)d_in[9];
    const float* be2w = (const float*)d_in[10]; const float* be2b = (const float*)d_in[11];
    const float* a2w  = (const float*)d_in[12]; const float* a2b  = (const float*)d_in[13];
    const float* ln1g = (const float*)d_in[14]; const float* ln1b = (const float*)d_in[15];
    const float* ln2g = (const float*)d_in[16]; const float* ln2b = (const float*)d_in[17];
    const float* wq   = (const float*)d_in[18]; const float* bq   = (const float*)d_in[19];
    const float* wk   = (const float*)d_in[20]; const float* bk   = (const float*)d_in[21];
    const float* wv   = (const float*)d_in[22]; const float* bv   = (const float*)d_in[23];
    const float* lvw  = (const float*)d_in[24]; const float* lvb  = (const float*)d_in[25];
    const float* f1w  = (const float*)d_in[26]; const float* f1b  = (const float*)d_in[27];
    const float* f2w  = (const float*)d_in[28]; const float* f2b  = (const float*)d_in[29];
    (void)in_sizes; (void)n_in; (void)out_size; (void)ws_size;

    // workspace layout (bytes) — ~222.7 MB total
    char* w8 = (char*)d_ws;
    float*  mod  = (float*)(w8);                                   //  98304
    bf16_t* wqT  = (bf16_t*)(w8 + 98304);                          // 4096x512 bf16
    bf16_t* wkT  = (bf16_t*)(w8 + 98304 + 4194304);
    bf16_t* wvT  = (bf16_t*)(w8 + 98304 + 2 * 4194304);
    bf16_t* lvwT = (bf16_t*)(w8 + 98304 + 3 * 4194304);            // 512x4096
    bf16_t* f1wT = (bf16_t*)(w8 + 98304 + 4 * 4194304);            // 2048x512
    bf16_t* f2wT = (bf16_t*)(w8 + 98304 + 4 * 4194304 + 2097152);  // 512x2048
    bf16_t* ybf  = (bf16_t*)(w8 + 98304 + 4 * 4194304 + 2 * 2097152);           // 8192x512
    bf16_t* qb   = (bf16_t*)(w8 + 98304 + 4 * 4194304 + 2 * 2097152 + 8388608); // (b,s,h,e); O in place; later relu buf
    bf16_t* kb   = qb + 33554432;    // (b,s,h,e)
    bf16_t* vtb  = kb + 33554432;    // V transposed: (b,h,e,s)

    static int fa_attr_done = 0;
    if (!fa_attr_done) {
        (void)hipFuncSetAttribute((const void*)flash_kernel,
                                  hipFuncAttributeMaxDynamicSharedMemorySize, FA_LDS);
        fa_attr_done = 1;
    }

    const dim3 blk(256);
    // weights -> bf16 transposed
    wtrans_kernel<<<dim3(128, 16), blk, 0, stream>>>(wq, wqT, 512, 4096);
    wtrans_kernel<<<dim3(128, 16), blk, 0, stream>>>(wk, wkT, 512, 4096);
    wtrans_kernel<<<dim3(128, 16), blk, 0, stream>>>(wv, wvT, 512, 4096);
    wtrans_kernel<<<dim3(16, 128), blk, 0, stream>>>(lvw, lvwT, 4096, 512);
    wtrans_kernel<<<dim3(64, 16), blk, 0, stream>>>(f1w, f1wT, 512, 2048);
    wtrans_kernel<<<dim3(16, 64), blk, 0, stream>>>(f2w, f2wT, 2048, 512);
    // modulation signals
    modsig_kernel<<<48, blk, 0, stream>>>(cond, g1w, be1w, a1w, g2w, be2w, a2w,
                                          g1b, be1b, a1b, g2b, be2b, a2b, mod);
    // LN1 + modulate -> y (bf16)
    ln_mod_kernel<<<8192, 128, 0, stream>>>(x, ln1g, ln1b, mod, mod + 4096, ybf);
    // QKV projections (V stored transposed)
    gemm128_kernel<0><<<dim3(32, 64), blk, 0, stream>>>(ybf, wqT, bq, qb,
        8192, 4096, 512, 512, 512, 4096);
    gemm128_kernel<0><<<dim3(32, 64), blk, 0, stream>>>(ybf, wkT, bk, kb,
        8192, 4096, 512, 512, 512, 4096);
    gemm128_kernel<3><<<dim3(32, 64), blk, 0, stream>>>(ybf, wvT, bv, vtb,
        8192, 4096, 512, 512, 512, 0);
    // fused flash attention: O overwrites qb
    flash_kernel<<<1024, 512, FA_LDS, stream>>>(qb, kb, vtb);
    // y2 = x + (O @ lvw + lvb) * alpha1 -> d_out (fp32)
    gemm64_kernel<<<dim3(4, 128), blk, 0, stream>>>(qb, lvwT, lvb, (float*)d_out, x, mod + 8192,
        8192, 512, 4096, 4096, 4096);
    // LN2 + modulate -> z (bf16)
    ln_mod_kernel<<<8192, 128, 0, stream>>>((const float*)d_out, ln2g, ln2b,
                                            mod + 12288, mod + 16384, ybf);
    // FFN
    gemm128_kernel<1><<<dim3(16, 64), blk, 0, stream>>>(ybf, f1wT, f1b, qb,
        8192, 2048, 512, 512, 512, 2048);
    gemm64_kernel<<<dim3(4, 128), blk, 0, stream>>>(qb, f2wT, f2b, (float*)d_out,
        (const float*)d_out, mod + 20480,
        8192, 512, 2048, 2048, 2048);
}

// Round 4
// 713.043 us; speedup vs baseline: 1.2396x; 1.0225x over previous
//
#include <hip/hip_runtime.h>
#include <hip/hip_bf16.h>

typedef __bf16 bf16_t;
typedef bf16_t bf16x8 __attribute__((ext_vector_type(8)));
typedef bf16_t bf16x4 __attribute__((ext_vector_type(4)));
typedef float f32x4 __attribute__((ext_vector_type(4)));

typedef const __attribute__((address_space(1))) void GV;
typedef __attribute__((address_space(3))) void LV;

__device__ __forceinline__ void gload_lds16(const bf16_t* gsrc, bf16_t* ldst) {
    __builtin_amdgcn_global_load_lds((GV*)gsrc, (LV*)ldst, 16, 0, 0);
}

// ---------------- weight transpose+convert: in fp32 (K x N) -> out bf16 (N x K)
__global__ __launch_bounds__(256) void wtrans_kernel(const float* __restrict__ in,
                                                     bf16_t* __restrict__ out, int K, int N)
{
    __shared__ float tile[32][33];
    const int n0 = blockIdx.x * 32, k0 = blockIdx.y * 32;
    const int tx = threadIdx.x & 31, ty = threadIdx.x >> 5;  // 32 x 8
#pragma unroll
    for (int i = 0; i < 32; i += 8)
        tile[ty + i][tx] = in[(long long)(k0 + ty + i) * N + n0 + tx];
    __syncthreads();
#pragma unroll
    for (int i = 0; i < 32; i += 8)
        out[(long long)(n0 + ty + i) * K + k0 + tx] = (bf16_t)tile[tx][ty + i];
}

// ---------------- 6 modulation linears on cond: out[(sig*8+b)*512 + n]
__global__ __launch_bounds__(256) void modsig_kernel(
    const float* __restrict__ cond,
    const float* __restrict__ w0, const float* __restrict__ w1, const float* __restrict__ w2,
    const float* __restrict__ w3, const float* __restrict__ w4, const float* __restrict__ w5,
    const float* __restrict__ c0, const float* __restrict__ c1, const float* __restrict__ c2,
    const float* __restrict__ c3, const float* __restrict__ c4, const float* __restrict__ c5,
    float* __restrict__ out)
{
    __shared__ float cs[512];
    const int sig = blockIdx.x >> 3, b = blockIdx.x & 7;
    const float* w; const float* bi;
    switch (sig) {
        case 0: w = w0; bi = c0; break;
        case 1: w = w1; bi = c1; break;
        case 2: w = w2; bi = c2; break;
        case 3: w = w3; bi = c3; break;
        case 4: w = w4; bi = c4; break;
        default: w = w5; bi = c5; break;
    }
    for (int i = threadIdx.x; i < 512; i += 256) cs[i] = cond[b * 512 + i];
    __syncthreads();
    for (int n = threadIdx.x; n < 512; n += 256) {
        float s = bi[n];
        for (int i = 0; i < 512; ++i) s = fmaf(cs[i], w[(long long)i * 512 + n], s);
        out[(long long)(sig * 8 + b) * 512 + n] = s;
    }
}

// ---------------- fused LayerNorm + AdaLN modulate, fp32 -> bf16
__global__ __launch_bounds__(128) void ln_mod_kernel(
    const float* __restrict__ x, const float* __restrict__ g, const float* __restrict__ be,
    const float* __restrict__ gamma, const float* __restrict__ beta, bf16_t* __restrict__ out)
{
    const int row = blockIdx.x;
    const int b = row >> 10;
    const int t = threadIdx.x;
    const float4 v = reinterpret_cast<const float4*>(x + (long long)row * 512)[t];
    float s = v.x + v.y + v.z + v.w;
    float ss = v.x * v.x + v.y * v.y + v.z * v.z + v.w * v.w;
    for (int o = 32; o; o >>= 1) { s += __shfl_xor(s, o); ss += __shfl_xor(ss, o); }
    __shared__ float red[4];
    if ((t & 63) == 0) { red[t >> 6] = s; red[2 + (t >> 6)] = ss; }
    __syncthreads();
    s = red[0] + red[1]; ss = red[2] + red[3];
    const float mu = s * (1.f / 512.f);
    const float rstd = rsqrtf(ss * (1.f / 512.f) - mu * mu + 1e-5f);
    const float4 gv = reinterpret_cast<const float4*>(g)[t];
    const float4 bv = reinterpret_cast<const float4*>(be)[t];
    const float4 ga = reinterpret_cast<const float4*>(gamma + b * 512)[t];
    const float4 bb = reinterpret_cast<const float4*>(beta + b * 512)[t];
    bf16x4 ov;
    ov[0] = (bf16_t)(((v.x - mu) * rstd * gv.x + bv.x) * (1.f + ga.x) + bb.x);
    ov[1] = (bf16_t)(((v.y - mu) * rstd * gv.y + bv.y) * (1.f + ga.y) + bb.y);
    ov[2] = (bf16_t)(((v.z - mu) * rstd * gv.z + bv.z) * (1.f + ga.z) + bb.z);
    ov[3] = (bf16_t)(((v.w - mu) * rstd * gv.w + bv.w) * (1.f + ga.w) + bb.w);
    reinterpret_cast<bf16x4*>(out + (long long)row * 512)[t] = ov;
}

// ---------------- 128x128x32 bf16 MFMA GEMM via global_load_lds, C = A * B^T
// LDS tiles [128 rows][4 chunks of 8 bf16], physical chunk = logical ^ (row&3)
// EPI 0: bf16 store (+bias)  EPI 1: relu->bf16 (+bias)  EPI 3: transposed-V layout
template <int EPI>
__global__ __launch_bounds__(256) void gemm128_kernel(
    const bf16_t* __restrict__ A, const bf16_t* __restrict__ B,
    const float* __restrict__ bias, void* Cout,
    int M, int N, int K, int lda, int ldb, int ldc)
{
    const int m0 = blockIdx.y * 128, n0 = blockIdx.x * 128;
    const int tid = threadIdx.x, lane = tid & 63, wid = tid >> 6;
    const int wr = wid >> 1, wc = wid & 1;

    __shared__ bf16_t As[4096];
    __shared__ bf16_t Bs[4096];

    f32x4 acc[4][4];
#pragma unroll
    for (int m = 0; m < 4; ++m)
#pragma unroll
        for (int n = 0; n < 4; ++n) acc[m][n] = (f32x4){0.f, 0.f, 0.f, 0.f};

    // staging: slot s holds row s>>2, physical chunk s&3 = logical (s&3)^(row&3)
    const int r0 = wid * 16 + (lane >> 2);
    const int lc = (lane & 3) ^ ((lane >> 2) & 3);
    const long long aOff0 = (long long)(m0 + r0) * lda + lc * 8;
    const long long aOff1 = (long long)(m0 + r0 + 64) * lda + lc * 8;
    const long long bOff0 = (long long)(n0 + r0) * ldb + lc * 8;
    const long long bOff1 = (long long)(n0 + r0 + 64) * ldb + lc * 8;
    bf16_t* aDst0 = As + wid * 512;
    bf16_t* aDst1 = As + 2048 + wid * 512;
    bf16_t* bDst0 = Bs + wid * 512;
    bf16_t* bDst1 = Bs + 2048 + wid * 512;

    const int frow = lane & 15, lg = lane >> 4;
    const int pc = lg ^ (frow & 3);

    for (int kt = 0; kt < K; kt += 32) {
        gload_lds16(A + aOff0 + kt, aDst0);
        gload_lds16(A + aOff1 + kt, aDst1);
        gload_lds16(B + bOff0 + kt, bDst0);
        gload_lds16(B + bOff1 + kt, bDst1);
        __syncthreads();
        bf16x8 af[4], bfv[4];
#pragma unroll
        for (int m = 0; m < 4; ++m)
            af[m] = *reinterpret_cast<const bf16x8*>(As + (wr * 64 + m * 16 + frow) * 32 + pc * 8);
#pragma unroll
        for (int n = 0; n < 4; ++n)
            bfv[n] = *reinterpret_cast<const bf16x8*>(Bs + (wc * 64 + n * 16 + frow) * 32 + pc * 8);
        __builtin_amdgcn_s_setprio(1);
#pragma unroll
        for (int m = 0; m < 4; ++m)
#pragma unroll
            for (int n = 0; n < 4; ++n)
                acc[m][n] = __builtin_amdgcn_mfma_f32_16x16x32_bf16(af[m], bfv[n], acc[m][n], 0, 0, 0);
        __builtin_amdgcn_s_setprio(0);
        __syncthreads();
    }

#pragma unroll
    for (int m = 0; m < 4; ++m) {
        const int gm = m0 + wr * 64 + m * 16 + ((lane >> 4) << 2);
#pragma unroll
        for (int n = 0; n < 4; ++n) {
            const int gn = n0 + wc * 64 + n * 16 + (lane & 15);
            const float bb = bias ? bias[gn] : 0.f;
#pragma unroll
            for (int j = 0; j < 4; ++j) {
                const float v = acc[m][n][j] + bb;
                const int gmj = gm + j;
                if (EPI == 0) {
                    ((bf16_t*)Cout)[(long long)gmj * ldc + gn] = (bf16_t)v;
                } else if (EPI == 1) {
                    ((bf16_t*)Cout)[(long long)gmj * ldc + gn] = (bf16_t)fmaxf(v, 0.f);
                } else {
                    const long long ci =
                        (long long)(((gmj >> 10) * 8 + (gn >> 9)) * 512 + (gn & 511)) * 1024 + (gmj & 1023);
                    ((bf16_t*)Cout)[ci] = (bf16_t)v;
                }
            }
        }
    }
}

// ---------------- 64x128x32 GEMM via global_load_lds, EPI2: out = resid + (acc+bias)*alpha
__global__ __launch_bounds__(256) void gemm64_kernel(
    const bf16_t* __restrict__ A, const bf16_t* __restrict__ B,
    const float* __restrict__ bias, float* __restrict__ Cout,
    const float* __restrict__ resid, const float* __restrict__ alpha,
    int M, int N, int K, int lda, int ldb)
{
    const int m0 = blockIdx.y * 64, n0 = blockIdx.x * 128;
    const int tid = threadIdx.x, lane = tid & 63, wid = tid >> 6;
    const int wr = wid >> 1, wc = wid & 1;

    __shared__ bf16_t As[2048];
    __shared__ bf16_t Bs[4096];

    f32x4 acc[2][4];
#pragma unroll
    for (int m = 0; m < 2; ++m)
#pragma unroll
        for (int n = 0; n < 4; ++n) acc[m][n] = (f32x4){0.f, 0.f, 0.f, 0.f};

    const int r0 = wid * 16 + (lane >> 2);
    const int lc = (lane & 3) ^ ((lane >> 2) & 3);
    const long long aOff0 = (long long)(m0 + r0) * lda + lc * 8;
    const long long bOff0 = (long long)(n0 + r0) * ldb + lc * 8;
    const long long bOff1 = (long long)(n0 + r0 + 64) * ldb + lc * 8;
    bf16_t* aDst0 = As + wid * 512;
    bf16_t* bDst0 = Bs + wid * 512;
    bf16_t* bDst1 = Bs + 2048 + wid * 512;

    const int frow = lane & 15, lg = lane >> 4;
    const int pc = lg ^ (frow & 3);

    for (int kt = 0; kt < K; kt += 32) {
        gload_lds16(A + aOff0 + kt, aDst0);
        gload_lds16(B + bOff0 + kt, bDst0);
        gload_lds16(B + bOff1 + kt, bDst1);
        __syncthreads();
        bf16x8 af[2], bfv[4];
#pragma unroll
        for (int m = 0; m < 2; ++m)
            af[m] = *reinterpret_cast<const bf16x8*>(As + (wr * 32 + m * 16 + frow) * 32 + pc * 8);
#pragma unroll
        for (int n = 0; n < 4; ++n)
            bfv[n] = *reinterpret_cast<const bf16x8*>(Bs + (wc * 64 + n * 16 + frow) * 32 + pc * 8);
        __builtin_amdgcn_s_setprio(1);
#pragma unroll
        for (int m = 0; m < 2; ++m)
#pragma unroll
            for (int n = 0; n < 4; ++n)
                acc[m][n] = __builtin_amdgcn_mfma_f32_16x16x32_bf16(af[m], bfv[n], acc[m][n], 0, 0, 0);
        __builtin_amdgcn_s_setprio(0);
        __syncthreads();
    }

#pragma unroll
    for (int m = 0; m < 2; ++m) {
        const int gm = m0 + wr * 32 + m * 16 + ((lane >> 4) << 2);
#pragma unroll
        for (int n = 0; n < 4; ++n) {
            const int gn = n0 + wc * 64 + n * 16 + (lane & 15);
            const float bb = bias[gn];
#pragma unroll
            for (int j = 0; j < 4; ++j) {
                const int gmj = gm + j;
                const long long ci = (long long)gmj * 512 + gn;
                Cout[ci] = resid[ci] + (acc[m][n][j] + bb) * alpha[(gmj >> 10) * 512 + gn];
            }
        }
    }
}

// ---------------- fused flash attention v2
// Q in registers; K/V in separate LDS buffers; 2 barriers/iter pipeline:
//   V(t)-load || S-phase ; K(t+1)-load || PV-phase
// delayed running max (m through tile t-1), double-buffered pmax/psum.
#define FA_LDS 141312
#define SCL 0.04508422132207354f   /* (1/32) * log2(e) */
__global__ __launch_bounds__(512, 2) void flash_kernel(
    bf16_t* __restrict__ qb, const bf16_t* __restrict__ kb, const bf16_t* __restrict__ vtb)
{
    extern __shared__ char smem[];
    bf16_t* Ks = (bf16_t*)smem;                 // [64][512], 16B chunk ^ (row&7)
    bf16_t* Vs = (bf16_t*)(smem + 65536);       // [512][64], 16B chunk ^ (e&7)
    char* PB = smem + 131072;                   // [64 q][64 k] bf16, 8B gran ^ ((q&7)<<1)
    float* pmaxB = (float*)(smem + 139264);     // [2][2][64]
    float* psumB = (float*)(smem + 140288);     // [2][2][64]

    const int bid = blockIdx.x;
    const int xcd = bid & 7, idx = bid >> 3;
    const int qt = idx & 15, bhl = idx >> 4;
    const int bh = xcd * 8 + bhl;
    const int b = bh >> 3, h = bh & 7;
    const int q0 = qt * 64;
    const int tid = threadIdx.x, lane = tid & 63, wid = tid >> 6;
    const int laneq = lane & 15, lx = lane & 7, lg = lane >> 4;
    const int wk = wid >> 2, wq = wid & 3;      // S role
    const int we = wid & 3, wq2 = wid >> 2;     // PV role

    // ---- prologue: stage K(0); load Q frags to registers
#pragma unroll
    for (int r = 0; r < 8; ++r) {
        const int row = r * 8 + wid;
        gload_lds16(kb + ((long long)(b * 1024 + row) * 8 + h) * 512 + ((lane ^ (row & 7)) << 3),
                    Ks + row * 512);
    }
    const int qi = wq * 16 + laneq;
    bf16x8 qfrag[16];
    {
        const bf16_t* qrow = qb + ((long long)(b * 1024 + q0 + qi) * 8 + h) * 512 + lg * 8;
#pragma unroll
        for (int ks = 0; ks < 16; ++ks) qfrag[ks] = *reinterpret_cast<const bf16x8*>(qrow + ks * 32);
    }
    f32x4 accA[8], accB[8];
#pragma unroll
    for (int e = 0; e < 8; ++e) { accA[e] = (f32x4){0.f,0.f,0.f,0.f}; accB[e] = (f32x4){0.f,0.f,0.f,0.f}; }
    float mS = 0.f, mPA = 0.f, mPB = 0.f, lA = 0.f, lB = 0.f;
    const int rA0 = wk * 32 + laneq, rA1 = rA0 + 16;
    const int qA = wq2 * 32 + laneq, qB = qA + 16;
    const int qx = (qi & 7) << 1;
    const int qxA = (qA & 7) << 1, qxB = (qB & 7) << 1;
    __syncthreads();

    for (int t = 0; t < 16; ++t) {
        const int kv0 = t * 64;
        // (a) issue V(t) staging — hidden under S-phase
#pragma unroll
        for (int r = 0; r < 8; ++r) {
            const int e = r * 64 + wid * 8 + (lane >> 3);
            gload_lds16(vtb + ((long long)bh * 512 + e) * 1024 + kv0 + ((lx ^ (e & 7)) << 3),
                        Vs + (r * 64 + wid * 8) * 64);
        }
        // (b) S-phase: S^T = K · Q^T
        f32x4 s0 = (f32x4){0.f,0.f,0.f,0.f}, s1 = (f32x4){0.f,0.f,0.f,0.f};
        const char* KsB = (const char*)Ks;
        __builtin_amdgcn_s_setprio(1);
#pragma unroll
        for (int ks = 0; ks < 16; ++ks) {
            const int co = ((ks * 4 + lg) ^ lx) << 4;
            bf16x8 a0 = *(const bf16x8*)(KsB + rA0 * 1024 + co);
            bf16x8 a1 = *(const bf16x8*)(KsB + rA1 * 1024 + co);
            s0 = __builtin_amdgcn_mfma_f32_16x16x32_bf16(a0, qfrag[ks], s0, 0, 0, 0);
            s1 = __builtin_amdgcn_mfma_f32_16x16x32_bf16(a1, qfrag[ks], s1, 0, 0, 0);
        }
        __builtin_amdgcn_s_setprio(0);
        // (c) delayed-max P = 2^(f - mS), partial max/sum, write P
        float f[8];
#pragma unroll
        for (int j = 0; j < 4; ++j) { f[j] = s0[j] * SCL; f[4 + j] = s1[j] * SCL; }
        float mloc = f[0];
#pragma unroll
        for (int j = 1; j < 8; ++j) mloc = fmaxf(mloc, f[j]);
        mloc = fmaxf(mloc, __shfl_xor(mloc, 16));
        mloc = fmaxf(mloc, __shfl_xor(mloc, 32));
        float pe[8]; float sl = 0.f;
#pragma unroll
        for (int j = 0; j < 8; ++j) { pe[j] = exp2f(f[j] - mS); sl += pe[j]; }
        sl += __shfl_xor(sl, 16);
        sl += __shfl_xor(sl, 32);
        if (lane < 16) {
            pmaxB[(t & 1) * 128 + wk * 64 + wq * 16 + lane] = mloc;
            psumB[(t & 1) * 128 + wk * 64 + wq * 16 + lane] = sl;
        }
        {
            bf16x4 p0, p1;
#pragma unroll
            for (int j = 0; j < 4; ++j) { p0[j] = (bf16_t)pe[j]; p1[j] = (bf16_t)pe[4 + j]; }
            const int kc0 = wk * 8 + lg, kc1 = kc0 + 4;
            *(bf16x4*)(PB + qi * 128 + ((kc0 ^ qx) << 3)) = p0;
            *(bf16x4*)(PB + qi * 128 + ((kc1 ^ qx) << 3)) = p1;
        }
        __syncthreads();  // (d): V(t)+P+stats ready (compiler drains vmcnt)

        // (e) issue K(t+1) staging — hidden under PV-phase
        if (t < 15) {
#pragma unroll
            for (int r = 0; r < 8; ++r) {
                const int row = r * 8 + wid;
                gload_lds16(kb + ((long long)(b * 1024 + kv0 + 64 + row) * 8 + h) * 512
                                + ((lane ^ (row & 7)) << 3),
                            Ks + row * 512);
            }
        }
        // (f) PV
        const char* VB = (const char*)Vs;
        __builtin_amdgcn_s_setprio(1);
#pragma unroll
        for (int ks2 = 0; ks2 < 2; ++ks2) {
            const int kcp = ks2 * 8 + lg * 2;
            bf16x8 pA = *(const bf16x8*)(PB + qA * 128 + ((kcp ^ qxA) << 3));
            bf16x8 pBv = *(const bf16x8*)(PB + qB * 128 + ((kcp ^ qxB) << 3));
            const int kcv = ks2 * 4 + lg;
#pragma unroll
            for (int ef = 0; ef < 8; ++ef) {
                const int re = we * 128 + ef * 16 + laneq;
                bf16x8 av = *(const bf16x8*)(VB + re * 128 + ((kcv ^ lx) << 4));
                accA[ef] = __builtin_amdgcn_mfma_f32_16x16x32_bf16(av, pA, accA[ef], 0, 0, 0);
                accB[ef] = __builtin_amdgcn_mfma_f32_16x16x32_bf16(av, pBv, accB[ef], 0, 0, 0);
            }
        }
        __builtin_amdgcn_s_setprio(0);
        // stats: accumulate in M(t) units, then rescale to M(t+1)
        {
            const float* pmax_t = pmaxB + (t & 1) * 128;
            const float* psum_t = psumB + (t & 1) * 128;
            mS = fmaxf(mS, fmaxf(pmax_t[qi], pmax_t[64 + qi]));
            lA += psum_t[qA] + psum_t[64 + qA];
            lB += psum_t[qB] + psum_t[64 + qB];
            const float mnA = fmaxf(mPA, fmaxf(pmax_t[qA], pmax_t[64 + qA]));
            const float mnB = fmaxf(mPB, fmaxf(pmax_t[qB], pmax_t[64 + qB]));
            if (__ballot((mnA > mPA) || (mnB > mPB))) {
                const float rA = exp2f(mPA - mnA), rB = exp2f(mPB - mnB);
                lA *= rA; lB *= rB;
#pragma unroll
                for (int e = 0; e < 8; ++e) {
#pragma unroll
                    for (int j = 0; j < 4; ++j) { accA[e][j] *= rA; accB[e][j] *= rB; }
                }
            }
            mPA = mnA; mPB = mnB;
        }
        __syncthreads();  // (g): K(t+1) ready; P/V reads done
    }

    // ---- epilogue: O = acc / l, store over qb
    const float iA = 1.f / lA, iB = 1.f / lB;
#pragma unroll
    for (int ef = 0; ef < 8; ++ef) {
        const int e0 = we * 128 + ef * 16 + lg * 4;
        bf16x4 oA, oB;
#pragma unroll
        for (int j = 0; j < 4; ++j) { oA[j] = (bf16_t)(accA[ef][j] * iA); oB[j] = (bf16_t)(accB[ef][j] * iB); }
        *(bf16x4*)(qb + ((long long)(b * 1024 + q0 + qA) * 8 + h) * 512 + e0) = oA;
        *(bf16x4*)(qb + ((long long)(b * 1024 + q0 + qB) * 8 + h) * 512 + e0) = oB;
    }
}

extern "C" void kernel_launch(void* const* d_in, const int* in_sizes, int n_in,
                              void* d_out, int out_size, void* d_ws, size_t ws_size,
                              hipStream_t stream)
{
    const float* x    = (const float*)d_in[0];
    const float* cond = (const float*)d_in[1];
    const float* g1w  = (const float*)d_in[2];  const float* g1b  = (const float*)d_in[3];
    const float* be1w = (const float*)d_in[4];  const float* be1b = (const float*)d_in[5];
    const float* a1w  = (const float*)d_in[6];  const float* a1b  = (const float*)d_in[7];
    const float* g2w  = (const float*)d_in[8];  const float* g2b  = (const float*)d_in[9];
    const float* be2w = (const float*)d_in[10]; const float* be2b = (const float*)d_in[11];
    const float* a2w  = (const float*)d_in[12]; const float* a2b  = (const float*)d_in[13];
    const float* ln1g = (const float*)d_in[14]; const float* ln1b = (const float*)d_in[15];
    const float* ln2g = (const float*)d_in[16]; const float* ln2b = (const float*)d_in[17];
    const float* wq   = (const float*)d_in[18]; const float* bq   = (const float*)d_in[19];
    const float* wk   = (const float*)d_in[20]; const float* bk   = (const float*)d_in[21];
    const float* wv   = (const float*)d_in[22]; const float* bv   = (const float*)d_in[23];
    const float* lvw  = (const float*)d_in[24]; const float* lvb  = (const float*)d_in[25];
    const float* f1w  = (const float*)d_in[26]; const float* f1b  = (const float*)d_in[27];
    const float* f2w  = (const float*)d_in[28]; const float* f2b  = (const float*)d_in[29];
    (void)in_sizes; (void)n_in; (void)out_size; (void)ws_size;

    // workspace layout (bytes)
    char* w8 = (char*)d_ws;
    float*  mod  = (float*)(w8);                                   //  98304
    bf16_t* wqT  = (bf16_t*)(w8 + 98304);                          // 4096x512 bf16
    bf16_t* wkT  = (bf16_t*)(w8 + 98304 + 4194304);
    bf16_t* wvT  = (bf16_t*)(w8 + 98304 + 2 * 4194304);
    bf16_t* lvwT = (bf16_t*)(w8 + 98304 + 3 * 4194304);            // 512x4096
    bf16_t* f1wT = (bf16_t*)(w8 + 98304 + 4 * 4194304);            // 2048x512
    bf16_t* f2wT = (bf16_t*)(w8 + 98304 + 4 * 4194304 + 2097152);  // 512x2048
    bf16_t* ybf  = (bf16_t*)(w8 + 98304 + 4 * 4194304 + 2 * 2097152);           // 8192x512
    bf16_t* qb   = (bf16_t*)(w8 + 98304 + 4 * 4194304 + 2 * 2097152 + 8388608); // (b,s,h,e); O in place
    bf16_t* kb   = qb + 33554432;    // (b,s,h,e)
    bf16_t* vtb  = kb + 33554432;    // V transposed: (b,h,e,s)

    (void)hipFuncSetAttribute((const void*)flash_kernel,
                              hipFuncAttributeMaxDynamicSharedMemorySize, FA_LDS);

    const dim3 blk(256);
    // weights -> bf16 transposed
    wtrans_kernel<<<dim3(128, 16), blk, 0, stream>>>(wq, wqT, 512, 4096);
    wtrans_kernel<<<dim3(128, 16), blk, 0, stream>>>(wk, wkT, 512, 4096);
    wtrans_kernel<<<dim3(128, 16), blk, 0, stream>>>(wv, wvT, 512, 4096);
    wtrans_kernel<<<dim3(16, 128), blk, 0, stream>>>(lvw, lvwT, 4096, 512);
    wtrans_kernel<<<dim3(64, 16), blk, 0, stream>>>(f1w, f1wT, 512, 2048);
    wtrans_kernel<<<dim3(16, 64), blk, 0, stream>>>(f2w, f2wT, 2048, 512);
    // modulation signals
    modsig_kernel<<<48, blk, 0, stream>>>(cond, g1w, be1w, a1w, g2w, be2w, a2w,
                                          g1b, be1b, a1b, g2b, be2b, a2b, mod);
    // LN1 + modulate -> y (bf16)
    ln_mod_kernel<<<8192, 128, 0, stream>>>(x, ln1g, ln1b, mod, mod + 4096, ybf);
    // QKV projections (V stored transposed)
    gemm128_kernel<0><<<dim3(32, 64), blk, 0, stream>>>(ybf, wqT, bq, qb,
        8192, 4096, 512, 512, 512, 4096);
    gemm128_kernel<0><<<dim3(32, 64), blk, 0, stream>>>(ybf, wkT, bk, kb,
        8192, 4096, 512, 512, 512, 4096);
    gemm128_kernel<3><<<dim3(32, 64), blk, 0, stream>>>(ybf, wvT, bv, vtb,
        8192, 4096, 512, 512, 512, 0);
    // fused flash attention: O overwrites qb
    flash_kernel<<<1024, 512, FA_LDS, stream>>>(qb, kb, vtb);
    // y2 = x + (O @ lvw + lvb) * alpha1 -> d_out (fp32)
    gemm64_kernel<<<dim3(4, 128), blk, 0, stream>>>(qb, lvwT, lvb, (float*)d_out, x, mod + 8192,
        8192, 512, 4096, 4096, 4096);
    // LN2 + modulate -> z (bf16)
    ln_mod_kernel<<<8192, 128, 0, stream>>>((const float*)d_out, ln2g, ln2b,
                                            mod + 12288, mod + 16384, ybf);
    // FFN
    gemm128_kernel<1><<<dim3(16, 64), blk, 0, stream>>>(ybf, f1wT, f1b, qb,
        8192, 2048, 512, 512, 512, 2048);
    gemm64_kernel<<<dim3(4, 128), blk, 0, stream>>>(qb, f2wT, f2b, (float*)d_out,
        (const float*)d_out, mod + 20480,
        8192, 512, 2048, 2048, 2048);
}